// Round 8
// baseline (193.554 us; speedup 1.0000x reference)
//
#include <hip/hip_runtime.h>

#define T_SEQ 50
#define BATCH 8192
#define INPUT 33
#define HID   256
#define BTILE 16
#define NTH   256   // 4 waves; grid=512 -> 2 independent blocks per CU

typedef __attribute__((ext_vector_type(8))) short short8;
typedef __attribute__((ext_vector_type(4))) float float4v;

// LDS: h double-buffer only. 16.9 KB/block -> 2 blocks/CU.
#define H_STRIDE 264                        // 256 + 8 pad
#define HBUF (BTILE * H_STRIDE)             // 4224 shorts
#define LDS_SHORTS (2 * HBUF)               // 16896 B

__device__ __forceinline__ short f2bf(float v) {   // RNE f32 -> bf16 bits
  unsigned u = __builtin_bit_cast(unsigned, v);
  u = (u + 0x7FFFu + ((u >> 16) & 1u)) >> 16;
  return (short)u;
}

#define MFMA(a, b, c) __builtin_amdgcn_mfma_f32_16x16x32_bf16(a, b, c, 0, 0, 0)

// One step. x for step T is already in registers (XC/X32C, loaded one step
// ahead); this step prefetches XN/X32N for T+1 at the TOP (before this step's
// stores -> loads are OLDER than stores -> their vmcnt wait next step cannot
// force store ACK). One lgkm-only barrier per step.
#define CSTEP(HR, HW, XC, X32C, XN, X32N, T)                                  \
  {                                                                           \
    const bool more = (T) + 1 < T_SEQ;                                        \
    if (more) {                                                               \
      const float* xt1 = xrow + (size_t)((T) + 1) * xstep;                    \
      _Pragma("unroll") for (int j = 0; j < 8; ++j) XN[j] = xt1[j];           \
      const float* xs1 = xcol32 + (size_t)((T) + 1) * xstep;                  \
      _Pragma("unroll") for (int i = 0; i < 4; ++i) X32N[i] = xs1[i * INPUT]; \
    }                                                                         \
    float4v acc[4];                                                           \
    _Pragma("unroll") for (int n = 0; n < 4; ++n)                             \
      _Pragma("unroll") for (int i = 0; i < 4; ++i)                           \
        acc[n][i] = hst[n][i] + bc[n];                                        \
    const short* hb = lds + (HR);                                             \
    _Pragma("unroll") for (int ks = 0; ks < 8; ++ks) {                        \
      short8 a0 = *(const short8*)(hb + colA * H_STRIDE + ks * 32 + kq * 8);  \
      acc[0] = MFMA(a0, wf[0][ks], acc[0]);                                   \
      acc[1] = MFMA(a0, wf[1][ks], acc[1]);                                   \
      acc[2] = MFMA(a0, wf[2][ks], acc[2]);                                   \
      acc[3] = MFMA(a0, wf[3][ks], acc[3]);                                   \
    }                                                                         \
    {                                                                         \
      short8 xa;                                                              \
      _Pragma("unroll") for (int j = 0; j < 8; ++j) xa[j] = f2bf(XC[j]);      \
      acc[0] = MFMA(xa, win0[0], acc[0]);                                     \
      acc[1] = MFMA(xa, win0[1], acc[1]);                                     \
      acc[2] = MFMA(xa, win0[2], acc[2]);                                     \
      acc[3] = MFMA(xa, win0[3], acc[3]);                                     \
    }                                                                         \
    _Pragma("unroll") for (int n = 0; n < 4; ++n)                             \
      _Pragma("unroll") for (int i = 0; i < 4; ++i)                           \
        acc[n][i] += w32[n] * X32C[i];                                        \
    _Pragma("unroll") for (int n = 0; n < 4; ++n)                             \
      _Pragma("unroll") for (int i = 0; i < 4; ++i) {                         \
        float hn = fmaxf(0.5f * acc[n][i], 0.0f);                             \
        hst[n][i] = hn;                                                       \
        outp[i * HID + n * 16] = hn;                                          \
      }                                                                       \
    _Pragma("unroll") for (int n = 0; n < 4; ++n)                             \
      _Pragma("unroll") for (int i = 0; i < 4; ++i)                           \
        lds[(HW) + (kq * 4 + i) * H_STRIDE + c0 + n * 16 + colA] =            \
            f2bf(hst[n][i]);                                                  \
    __builtin_amdgcn_sched_barrier(0);                                        \
    asm volatile("s_waitcnt lgkmcnt(0)" ::: "memory");                        \
    __builtin_amdgcn_s_barrier();                                             \
    __builtin_amdgcn_sched_barrier(0);                                        \
    outp += outstep;                                                          \
  }

__global__ __launch_bounds__(NTH, 2)
void ctrnn_kernel(const float* __restrict__ x, const int* __restrict__ sub_id,
                  const float* __restrict__ gates, const float* __restrict__ W_in,
                  const float* __restrict__ b_in, const float* __restrict__ W_h,
                  const float* __restrict__ b_h, float* __restrict__ out)
{
  __shared__ short lds[LDS_SHORTS];
  const int tid  = threadIdx.x;
  const int lane = tid & 63;
  const int wave = tid >> 6;    // 0..3
  const int colA = lane & 15;   // A-row (batch row) / C-col within tile
  const int kq   = lane >> 4;   // k-chunk / C-row group
  const int c0   = wave * 64;   // wave's output-column base (4 waves x 64)
  const int brow0 = blockIdx.x * BTILE;

  const int sid = sub_id[0];
  const float* grow = gates + sid * HID;

  // ---- zero h buffer 0 (h0 = 0) ----
  {
    int* ldsi = (int*)lds;
    for (int i = tid; i < HBUF / 2; i += NTH) ldsi[i] = 0;
  }

  // ---- t-invariant operands in registers (per wave: 64 out-cols) ----
  short8 wf[4][8];    // W_h' = diag(g)*W_h B-fragments (128 VGPRs)
  short8 win0[4];     // W_in k=0..31 B-fragments
  float  w32[4];      // W_in k=32 column (rank-1, f32)
  float  bc[4];       // b_in + g*b_h
  #pragma unroll
  for (int n = 0; n < 4; ++n) {
    const int col = c0 + n * 16 + colA;
    const float g = grow[col];
    #pragma unroll
    for (int ks = 0; ks < 8; ++ks) {
      const float* wp = W_h + col * HID + ks * 32 + kq * 8;
      float4v w0 = *(const float4v*)wp;
      float4v w1 = *(const float4v*)(wp + 4);
      short8 f;
      f[0] = f2bf(g * w0[0]); f[1] = f2bf(g * w0[1]);
      f[2] = f2bf(g * w0[2]); f[3] = f2bf(g * w0[3]);
      f[4] = f2bf(g * w1[0]); f[5] = f2bf(g * w1[1]);
      f[6] = f2bf(g * w1[2]); f[7] = f2bf(g * w1[3]);
      wf[n][ks] = f;
    }
    {
      const float* wip = W_in + col * INPUT + kq * 8;   // k = kq*8..kq*8+7 < 32
      short8 f;
      #pragma unroll
      for (int j = 0; j < 8; ++j) f[j] = f2bf(wip[j]);
      win0[n] = f;
    }
    w32[n] = W_in[col * INPUT + 32];
    bc[n]  = b_in[col] + g * b_h[col];
  }

  // x addressing: A-frag row = colA, k = kq*8..kq*8+7 (all < 32);
  // k=32 column for C-rows kq*4..kq*4+3 (rank-1 term).
  const float* xrow   = x + (size_t)(brow0 + colA) * INPUT + kq * 8;
  const float* xcol32 = x + (size_t)(brow0 + kq * 4) * INPUT + 32;
  const int xstep = BATCH * INPUT;

  // x pipeline registers (A set / B set alternate per step)
  float xA[8], x32A[4], xB[8], x32B[4];
  {
    #pragma unroll
    for (int j = 0; j < 8; ++j) xA[j] = xrow[j];
    #pragma unroll
    for (int i = 0; i < 4; ++i) x32A[i] = xcol32[i * INPUT];
  }

  // persistent f32 h master at MFMA C-layout: col=c0+n*16+colA, row=kq*4+i
  float4v hst[4];
  #pragma unroll
  for (int n = 0; n < 4; ++n)
    #pragma unroll
    for (int i = 0; i < 4; ++i) hst[n][i] = 0.0f;

  float* outp = out + (size_t)(brow0 + kq * 4) * HID + c0 + colA;
  const int outstep = BATCH * HID;

  __syncthreads();   // h0 zero-fill visible

  #pragma unroll 1
  for (int t2 = 0; t2 < T_SEQ / 2; ++t2) {
    CSTEP(0, HBUF, xA, x32A, xB, x32B, 2 * t2);        // even: read buf0
    CSTEP(HBUF, 0, xB, x32B, xA, x32A, 2 * t2 + 1);    // odd:  read buf1
  }

  // h_last = h after step T-1 (in registers)
  {
    float* hp = out + (size_t)T_SEQ * BATCH * HID +
                (size_t)(brow0 + kq * 4) * HID + c0 + colA;
    #pragma unroll
    for (int n = 0; n < 4; ++n)
      #pragma unroll
      for (int i = 0; i < 4; ++i)
        hp[i * HID + n * 16] = hst[n][i];
  }
}

extern "C" void kernel_launch(void* const* d_in, const int* in_sizes, int n_in,
                              void* d_out, int out_size, void* d_ws, size_t ws_size,
                              hipStream_t stream) {
  const float* x    = (const float*)d_in[0];
  const int*   sid  = (const int*)  d_in[1];
  const float* gts  = (const float*)d_in[2];
  const float* W_in = (const float*)d_in[3];
  const float* b_in = (const float*)d_in[4];
  const float* W_h  = (const float*)d_in[5];
  const float* b_h  = (const float*)d_in[6];
  float* out = (float*)d_out;

  ctrnn_kernel<<<BATCH / BTILE, NTH, 0, stream>>>(x, sid, gts, W_in, b_in, W_h, b_h, out);
}

// Round 9
// 161.745 us; speedup vs baseline: 1.1967x; 1.1967x over previous
//
#include <hip/hip_runtime.h>

#define T_SEQ 50
#define BATCH 8192
#define INPUT 33
#define HID   256
#define BTILE 32
#define NTH   512

typedef __attribute__((ext_vector_type(8))) short short8;
typedef __attribute__((ext_vector_type(4))) float float4v;

// LDS (shorts): h dbuf + x dbuf = 43008 B -> 86 KB for 2 blocks/CU.
#define H_STRIDE 264                       // 256 + 8 pad
#define X_STRIDE 72                        // 64 + 8 pad (cols: 0..32 x, 33 = 1.0, rest 0)
#define H0 0
#define H1 (BTILE * H_STRIDE)              // 8448
#define X0 (2 * BTILE * H_STRIDE)          // 16896
#define X1 (X0 + BTILE * X_STRIDE)         // 19200
#define LDS_SHORTS (X1 + BTILE * X_STRIDE) // 21504 shorts = 43008 B

__device__ __forceinline__ short f2bf(float v) {   // RNE f32 -> bf16 bits
  unsigned u = __builtin_bit_cast(unsigned, v);
  u = (u + 0x7FFFu + ((u >> 16) & 1u)) >> 16;
  return (short)u;
}

#define MFMA(a, b, c) __builtin_amdgcn_mfma_f32_16x16x32_bf16(a, b, c, 0, 0, 0)

// One step. MFMA accumulates IN PLACE on hst (C-in = h implements h + pre;
// bc rides in win[.][1] against the constant-1.0 x column). One lgkm-only
// barrier; stores never drained in-loop.
#define CSTEP(HR, XR, HW, XW, T)                                              \
  {                                                                           \
    float xp0 = 0.f, xp1 = 0.f, xp2 = 0.f;                                    \
    const bool more = (T) + 1 < T_SEQ;                                        \
    if (more) {                                                               \
      const float* xt1 = xpf + (size_t)((T) + 1) * xstep;                     \
      xp0 = xt1[e0]; xp1 = xt1[e1];                                           \
      if (p2) xp2 = xt1[e2];                                                  \
    }                                                                         \
    const short* hb = lds + (HR);                                             \
    const short* xb = lds + (XR);                                             \
    _Pragma("unroll") for (int ks = 0; ks < 8; ++ks) {                        \
      const int k = ks * 32 + kq * 8;                                         \
      short8 a0 = *(const short8*)(hb + colA * H_STRIDE + k);                 \
      short8 a1 = *(const short8*)(hb + (16 + colA) * H_STRIDE + k);          \
      hst[0][0] = MFMA(a0, wf[0][ks], hst[0][0]);                             \
      hst[0][1] = MFMA(a0, wf[1][ks], hst[0][1]);                             \
      hst[1][0] = MFMA(a1, wf[0][ks], hst[1][0]);                             \
      hst[1][1] = MFMA(a1, wf[1][ks], hst[1][1]);                             \
    }                                                                         \
    _Pragma("unroll") for (int kb = 0; kb < 2; ++kb) {                        \
      const int k = kb * 32 + kq * 8;                                         \
      short8 a0 = *(const short8*)(xb + colA * X_STRIDE + k);                 \
      short8 a1 = *(const short8*)(xb + (16 + colA) * X_STRIDE + k);          \
      hst[0][0] = MFMA(a0, win[0][kb], hst[0][0]);                            \
      hst[0][1] = MFMA(a0, win[1][kb], hst[0][1]);                            \
      hst[1][0] = MFMA(a1, win[0][kb], hst[1][0]);                            \
      hst[1][1] = MFMA(a1, win[1][kb], hst[1][1]);                            \
    }                                                                         \
    _Pragma("unroll") for (int m = 0; m < 2; ++m)                             \
      _Pragma("unroll") for (int n = 0; n < 2; ++n)                           \
        _Pragma("unroll") for (int i = 0; i < 4; ++i) {                       \
          float hn = fmaxf(0.5f * hst[m][n][i], 0.0f);                        \
          hst[m][n][i] = hn;                                                  \
          (m == 0 ? outp0 : outp0 + 16 * HID)[i * HID + n * 16] = hn;         \
        }                                                                     \
    _Pragma("unroll") for (int m = 0; m < 2; ++m)                             \
      _Pragma("unroll") for (int n = 0; n < 2; ++n)                           \
        _Pragma("unroll") for (int i = 0; i < 4; ++i)                         \
          lds[(HW) + (m * 16 + kq * 4 + i) * H_STRIDE + c0 + n * 16 + colA] = \
              f2bf(hst[m][n][i]);                                             \
    if (more) {                                                               \
      lds[(XW) + r0 * X_STRIDE + c0x] = f2bf(xp0);                            \
      lds[(XW) + r1 * X_STRIDE + c1x] = f2bf(xp1);                            \
      if (p2) lds[(XW) + r2 * X_STRIDE + c2x] = f2bf(xp2);                    \
    }                                                                         \
    __builtin_amdgcn_sched_barrier(0);                                        \
    asm volatile("s_waitcnt lgkmcnt(0)" ::: "memory");                        \
    __builtin_amdgcn_s_barrier();                                             \
    __builtin_amdgcn_sched_barrier(0);                                        \
    outp0 += outstep;                                                         \
  }

__global__ __launch_bounds__(NTH, 4)
void ctrnn_kernel(const float* __restrict__ x, const int* __restrict__ sub_id,
                  const float* __restrict__ gates, const float* __restrict__ W_in,
                  const float* __restrict__ b_in, const float* __restrict__ W_h,
                  const float* __restrict__ b_h, float* __restrict__ out)
{
  __shared__ short lds[LDS_SHORTS];
  const int tid  = threadIdx.x;
  const int lane = tid & 63;
  const int wave = tid >> 6;
  const int colA = lane & 15;   // A-row (batch) / C-col within tile
  const int kq   = lane >> 4;   // k-chunk / C-row group
  const int c0   = wave * 32;   // wave's output-column base (8 waves x 32)
  const int brow0 = blockIdx.x * BTILE;

  const int sid = sub_id[0];
  const float* grow = gates + sid * HID;

  // ---- zero all LDS; then x col 33 = 1.0 (bf16 0x3F80) in BOTH x buffers ----
  {
    int* ldsi = (int*)lds;
    for (int i = tid; i < LDS_SHORTS / 2; i += NTH) ldsi[i] = 0;
  }
  __syncthreads();
  if (tid < 2 * BTILE) {
    int b = tid >> 5, r = tid & 31;
    lds[(b ? X1 : X0) + r * X_STRIDE + 33] = (short)0x3F80;
  }

  // ---- t-invariant operands in registers ----
  short8 wf[2][8];   // W_h' = diag(g)*W_h B-fragments (64 VGPRs)
  short8 win[2][2];  // W_in k=0..32 B-fragments; k=33 slot carries bc
  #pragma unroll
  for (int n = 0; n < 2; ++n) {
    const int col = c0 + n * 16 + colA;
    const float g = grow[col];
    #pragma unroll
    for (int ks = 0; ks < 8; ++ks) {
      const float* wp = W_h + col * HID + ks * 32 + kq * 8;
      float4v w0 = *(const float4v*)wp;
      float4v w1 = *(const float4v*)(wp + 4);
      short8 f;
      f[0] = f2bf(g * w0[0]); f[1] = f2bf(g * w0[1]);
      f[2] = f2bf(g * w0[2]); f[3] = f2bf(g * w0[3]);
      f[4] = f2bf(g * w1[0]); f[5] = f2bf(g * w1[1]);
      f[6] = f2bf(g * w1[2]); f[7] = f2bf(g * w1[3]);
      wf[n][ks] = f;
    }
    const float bcv = b_in[col] + g * b_h[col];
    #pragma unroll
    for (int kb = 0; kb < 2; ++kb) {
      short8 f;
      #pragma unroll
      for (int j = 0; j < 8; ++j) {
        const int kk = kb * 32 + kq * 8 + j;
        float v = (kk < INPUT) ? W_in[col * INPUT + kk]
                               : (kk == INPUT ? bcv : 0.0f);
        f[j] = f2bf(v);
      }
      win[n][kb] = f;
    }
  }

  __syncthreads();   // zero + col-33 writes complete before x0 staging

  // ---- stage x_0 into buffer 0 ----
  {
    const float* xt = x + (size_t)brow0 * INPUT;
    for (int e = tid; e < BTILE * INPUT; e += NTH) {
      int r = e / INPUT, c = e - r * INPUT;
      lds[X0 + r * X_STRIDE + c] = f2bf(xt[e]);
    }
  }

  // x-prefetch invariants (1056 elems over 512 threads, 3 rounds)
  const int e0 = tid, e1 = tid + NTH, e2 = tid + 2 * NTH;
  const int r0 = e0 / INPUT, c0x = e0 - r0 * INPUT;
  const int r1 = e1 / INPUT, c1x = e1 - r1 * INPUT;
  const int r2 = e2 / INPUT, c2x = e2 - r2 * INPUT;
  const bool p2 = (e2 < BTILE * INPUT);

  // persistent f32 h at MFMA C-layout; MFMA accumulates in place on it
  float4v hst[2][2];
  #pragma unroll
  for (int m = 0; m < 2; ++m)
    #pragma unroll
    for (int n = 0; n < 2; ++n)
      #pragma unroll
      for (int i = 0; i < 4; ++i) hst[m][n][i] = 0.0f;

  float* outp0 = out + (size_t)(brow0 + kq * 4) * HID + c0 + colA;
  const int outstep = BATCH * HID;
  const float* xpf = x + (size_t)brow0 * INPUT;
  const int xstep = BATCH * INPUT;

  __syncthreads();   // x0 staged; h0 zeroed

  #pragma unroll 1
  for (int t2 = 0; t2 < T_SEQ / 2; ++t2) {
    CSTEP(H0, X0, H1, X1, 2 * t2);       // even: read buf0, write buf1
    CSTEP(H1, X1, H0, X0, 2 * t2 + 1);   // odd:  read buf1, write buf0
  }

  // h_last = h after step T-1 (in registers)
  {
    float* hp = out + (size_t)T_SEQ * BATCH * HID +
                (size_t)(brow0 + kq * 4) * HID + c0 + colA;
    #pragma unroll
    for (int m = 0; m < 2; ++m)
      #pragma unroll
      for (int n = 0; n < 2; ++n)
        #pragma unroll
        for (int i = 0; i < 4; ++i)
          hp[(m * 16 + i) * HID + n * 16] = hst[m][n][i];
  }
}

extern "C" void kernel_launch(void* const* d_in, const int* in_sizes, int n_in,
                              void* d_out, int out_size, void* d_ws, size_t ws_size,
                              hipStream_t stream) {
  const float* x    = (const float*)d_in[0];
  const int*   sid  = (const int*)  d_in[1];
  const float* gts  = (const float*)d_in[2];
  const float* W_in = (const float*)d_in[3];
  const float* b_in = (const float*)d_in[4];
  const float* W_h  = (const float*)d_in[5];
  const float* b_h  = (const float*)d_in[6];
  float* out = (float*)d_out;

  ctrnn_kernel<<<BATCH / BTILE, NTH, 0, stream>>>(x, sid, gts, W_in, b_in, W_h, b_h, out);
}

// Round 10
// 127.902 us; speedup vs baseline: 1.5133x; 1.2646x over previous
//
#include <hip/hip_runtime.h>

#define T_SEQ 50
#define BATCH 8192
#define INPUT 33
#define HID   256
#define BTILE 32
#define NTH   512

typedef __attribute__((ext_vector_type(8))) short short8;
typedef __attribute__((ext_vector_type(4))) short short4v;
typedef __attribute__((ext_vector_type(4))) float float4v;

// LDS (shorts): h dbuf + x dbuf = 43008 B. 1 block/CU, 8 waves.
#define H_STRIDE 264                       // 256 + 8 pad
#define X_STRIDE 72                        // 64 + 8 pad (cols: 0..32 x, 33 = 1.0, rest 0)
#define H0 0
#define H1 (BTILE * H_STRIDE)              // 8448
#define X0 (2 * BTILE * H_STRIDE)          // 16896
#define X1 (X0 + BTILE * X_STRIDE)         // 19200
#define LDS_SHORTS (X1 + BTILE * X_STRIDE) // 21504 shorts = 43008 B

__device__ __forceinline__ short f2bf(float v) {   // RNE f32 -> bf16 bits
  unsigned u = __builtin_bit_cast(unsigned, v);
  u = (u + 0x7FFFu + ((u >> 16) & 1u)) >> 16;
  return (short)u;
}

#define MFMA(a, b, c) __builtin_amdgcn_mfma_f32_16x16x32_bf16(a, b, c, 0, 0, 0)

// SWAPPED-OPERAND step: C = W'·h^T, so C rows = hidden-j (kq*4+i), C cols =
// batch (colA). Each thread owns 4 CONSECUTIVE j for one batch row per tile:
//   - global stores: 4 x dwordx4 (was 16 scattered dwords)
//   - h restage:     4 x ds_write_b64 (was 16 scalar b16 writes)
// MFMA accumulates in place on hst (C-in = h; bc rides in win[.][1] k=33
// against the constant-1.0 x column). One lgkm-only barrier per step.
#define CSTEP(HR, XR, HW, XW, T)                                              \
  {                                                                           \
    float xp0 = 0.f, xp1 = 0.f, xp2 = 0.f;                                    \
    const bool more = (T) + 1 < T_SEQ;                                        \
    if (more) {                                                               \
      const float* xt1 = xpf + (size_t)((T) + 1) * xstep;                     \
      xp0 = xt1[e0]; xp1 = xt1[e1];                                           \
      if (p2) xp2 = xt1[e2];                                                  \
    }                                                                         \
    const short* hb = lds + (HR);                                             \
    const short* xb = lds + (XR);                                             \
    _Pragma("unroll") for (int ks = 0; ks < 8; ++ks) {                        \
      const int k = ks * 32 + kq * 8;                                         \
      short8 b0 = *(const short8*)(hb + colA * H_STRIDE + k);                 \
      short8 b1 = *(const short8*)(hb + (16 + colA) * H_STRIDE + k);          \
      hst[0][0] = MFMA(wf[0][ks], b0, hst[0][0]);                             \
      hst[0][1] = MFMA(wf[0][ks], b1, hst[0][1]);                             \
      hst[1][0] = MFMA(wf[1][ks], b0, hst[1][0]);                             \
      hst[1][1] = MFMA(wf[1][ks], b1, hst[1][1]);                             \
    }                                                                         \
    _Pragma("unroll") for (int kb = 0; kb < 2; ++kb) {                        \
      const int k = kb * 32 + kq * 8;                                         \
      short8 b0 = *(const short8*)(xb + colA * X_STRIDE + k);                 \
      short8 b1 = *(const short8*)(xb + (16 + colA) * X_STRIDE + k);          \
      hst[0][0] = MFMA(win[0][kb], b0, hst[0][0]);                            \
      hst[0][1] = MFMA(win[0][kb], b1, hst[0][1]);                            \
      hst[1][0] = MFMA(win[1][kb], b0, hst[1][0]);                            \
      hst[1][1] = MFMA(win[1][kb], b1, hst[1][1]);                            \
    }                                                                         \
    _Pragma("unroll") for (int jt = 0; jt < 2; ++jt)                          \
      _Pragma("unroll") for (int bt = 0; bt < 2; ++bt) {                      \
        float4v hv;                                                           \
        _Pragma("unroll") for (int i = 0; i < 4; ++i) {                       \
          float hn = fmaxf(0.5f * hst[jt][bt][i], 0.0f);                      \
          hst[jt][bt][i] = hn;                                                \
          hv[i] = hn;                                                         \
        }                                                                     \
        *(float4v*)(outp + (size_t)(bt * 16) * HID + jt * 16) = hv;           \
        short4v hs;                                                           \
        hs[0] = f2bf(hv[0]); hs[1] = f2bf(hv[1]);                             \
        hs[2] = f2bf(hv[2]); hs[3] = f2bf(hv[3]);                             \
        *(short4v*)(lds + (HW) + (bt * 16 + colA) * H_STRIDE + c0 + jt * 16 + \
                    kq * 4) = hs;                                             \
      }                                                                       \
    if (more) {                                                               \
      lds[(XW) + r0 * X_STRIDE + c0x] = f2bf(xp0);                            \
      lds[(XW) + r1 * X_STRIDE + c1x] = f2bf(xp1);                            \
      if (p2) lds[(XW) + r2 * X_STRIDE + c2x] = f2bf(xp2);                    \
    }                                                                         \
    __builtin_amdgcn_sched_barrier(0);                                        \
    asm volatile("s_waitcnt lgkmcnt(0)" ::: "memory");                        \
    __builtin_amdgcn_s_barrier();                                             \
    __builtin_amdgcn_sched_barrier(0);                                        \
    outp += outstep;                                                          \
  }

__global__ __launch_bounds__(NTH, 2)
void ctrnn_kernel(const float* __restrict__ x, const int* __restrict__ sub_id,
                  const float* __restrict__ gates, const float* __restrict__ W_in,
                  const float* __restrict__ b_in, const float* __restrict__ W_h,
                  const float* __restrict__ b_h, float* __restrict__ out)
{
  __shared__ short lds[LDS_SHORTS];
  const int tid  = threadIdx.x;
  const int lane = tid & 63;
  const int wave = tid >> 6;
  const int colA = lane & 15;   // batch row within tile (B-frag col / C col)
  const int kq   = lane >> 4;   // k-chunk; C rows = j = kq*4+i
  const int c0   = wave * 32;   // wave's hidden-j base (8 waves x 32 j)
  const int brow0 = blockIdx.x * BTILE;

  const int sid = sub_id[0];
  const float* grow = gates + sid * HID;

  // ---- zero all LDS; then x col 33 = 1.0 (bf16 0x3F80) in BOTH x buffers ----
  {
    int* ldsi = (int*)lds;
    for (int i = tid; i < LDS_SHORTS / 2; i += NTH) ldsi[i] = 0;
  }
  __syncthreads();
  if (tid < 2 * BTILE) {
    int b = tid >> 5, r = tid & 31;
    lds[(b ? X1 : X0) + r * X_STRIDE + 33] = (short)0x3F80;
  }

  // ---- t-invariant operands in registers (now the MFMA *A* operands) ----
  short8 wf[2][8];   // W_h' = diag(g)*W_h fragments: A[j=c0+jt*16+colA][k]
  short8 win[2][2];  // W_in fragments, k=33 slot carries bc
  #pragma unroll
  for (int jt = 0; jt < 2; ++jt) {
    const int col = c0 + jt * 16 + colA;
    const float g = grow[col];
    #pragma unroll
    for (int ks = 0; ks < 8; ++ks) {
      const float* wp = W_h + col * HID + ks * 32 + kq * 8;
      float4v w0 = *(const float4v*)wp;
      float4v w1 = *(const float4v*)(wp + 4);
      short8 f;
      f[0] = f2bf(g * w0[0]); f[1] = f2bf(g * w0[1]);
      f[2] = f2bf(g * w0[2]); f[3] = f2bf(g * w0[3]);
      f[4] = f2bf(g * w1[0]); f[5] = f2bf(g * w1[1]);
      f[6] = f2bf(g * w1[2]); f[7] = f2bf(g * w1[3]);
      wf[jt][ks] = f;
    }
    const float bcv = b_in[col] + g * b_h[col];
    #pragma unroll
    for (int kb = 0; kb < 2; ++kb) {
      short8 f;
      #pragma unroll
      for (int j = 0; j < 8; ++j) {
        const int kk = kb * 32 + kq * 8 + j;
        float v = (kk < INPUT) ? W_in[col * INPUT + kk]
                               : (kk == INPUT ? bcv : 0.0f);
        f[j] = f2bf(v);
      }
      win[jt][kb] = f;
    }
  }

  __syncthreads();   // zero + col-33 writes complete before x0 staging

  // ---- stage x_0 into buffer 0 ----
  {
    const float* xt = x + (size_t)brow0 * INPUT;
    for (int e = tid; e < BTILE * INPUT; e += NTH) {
      int r = e / INPUT, c = e - r * INPUT;
      lds[X0 + r * X_STRIDE + c] = f2bf(xt[e]);
    }
  }

  // x-prefetch invariants (1056 elems over 512 threads, 3 rounds)
  const int e0 = tid, e1 = tid + NTH, e2 = tid + 2 * NTH;
  const int r0 = e0 / INPUT, c0x = e0 - r0 * INPUT;
  const int r1 = e1 / INPUT, c1x = e1 - r1 * INPUT;
  const int r2 = e2 / INPUT, c2x = e2 - r2 * INPUT;
  const bool p2 = (e2 < BTILE * INPUT);

  // persistent f32 h at swapped C-layout: hst[jt][bt][i] =
  //   h[b = brow0 + bt*16 + colA][j = c0 + jt*16 + kq*4 + i]
  float4v hst[2][2];
  #pragma unroll
  for (int jt = 0; jt < 2; ++jt)
    #pragma unroll
    for (int bt = 0; bt < 2; ++bt)
      #pragma unroll
      for (int i = 0; i < 4; ++i) hst[jt][bt][i] = 0.0f;

  // store base: batch row = brow0 + bt*16 + colA, j base = c0 + jt*16 + kq*4
  float* outp = out + (size_t)(brow0 + colA) * HID + c0 + kq * 4;
  const int outstep = BATCH * HID;
  const float* xpf = x + (size_t)brow0 * INPUT;
  const int xstep = BATCH * INPUT;

  __syncthreads();   // x0 staged; h0 zeroed

  #pragma unroll 1
  for (int t2 = 0; t2 < T_SEQ / 2; ++t2) {
    CSTEP(H0, X0, H1, X1, 2 * t2);       // even: read buf0, write buf1
    CSTEP(H1, X1, H0, X0, 2 * t2 + 1);   // odd:  read buf1, write buf0
  }

  // h_last = h after step T-1 (in registers)
  {
    float* hp = out + (size_t)T_SEQ * BATCH * HID +
                (size_t)(brow0 + colA) * HID + c0 + kq * 4;
    #pragma unroll
    for (int jt = 0; jt < 2; ++jt)
      #pragma unroll
      for (int bt = 0; bt < 2; ++bt) {
        float4v hv;
        #pragma unroll
        for (int i = 0; i < 4; ++i) hv[i] = hst[jt][bt][i];
        *(float4v*)(hp + (size_t)(bt * 16) * HID + jt * 16) = hv;
      }
  }
}

extern "C" void kernel_launch(void* const* d_in, const int* in_sizes, int n_in,
                              void* d_out, int out_size, void* d_ws, size_t ws_size,
                              hipStream_t stream) {
  const float* x    = (const float*)d_in[0];
  const int*   sid  = (const int*)  d_in[1];
  const float* gts  = (const float*)d_in[2];
  const float* W_in = (const float*)d_in[3];
  const float* b_in = (const float*)d_in[4];
  const float* W_h  = (const float*)d_in[5];
  const float* b_h  = (const float*)d_in[6];
  float* out = (float*)d_out;

  ctrnn_kernel<<<BATCH / BTILE, NTH, 0, stream>>>(x, sid, gts, W_in, b_in, W_h, b_h, out);
}

// Round 11
// 119.309 us; speedup vs baseline: 1.6223x; 1.0720x over previous
//
#include <hip/hip_runtime.h>

#define T_SEQ 50
#define BATCH 8192
#define INPUT 33
#define HID   256
#define BTILE 32
#define NTH   1024   // 16 waves, ONE block/CU -> 4 waves/SIMD (the lever)

typedef __attribute__((ext_vector_type(8))) short short8;
typedef __attribute__((ext_vector_type(4))) float float4v;

// LDS (shorts): h dbuf + x dbuf = 43008 B. 1 block/CU, 16 waves.
#define H_STRIDE 264                       // 256 + 8 pad
#define X_STRIDE 72                        // 64 + 8 pad (cols: 0..32 x, 33 = 1.0, rest 0)
#define H0 0
#define H1 (BTILE * H_STRIDE)              // 8448
#define X0 (2 * BTILE * H_STRIDE)          // 16896
#define X1 (X0 + BTILE * X_STRIDE)         // 19200
#define LDS_SHORTS (X1 + BTILE * X_STRIDE) // 21504 shorts = 43008 B

__device__ __forceinline__ short f2bf(float v) {   // RNE f32 -> bf16 bits
  unsigned u = __builtin_bit_cast(unsigned, v);
  u = (u + 0x7FFFu + ((u >> 16) & 1u)) >> 16;
  return (short)u;
}

#define MFMA(a, b, c) __builtin_amdgcn_mfma_f32_16x16x32_bf16(a, b, c, 0, 0, 0)

// One step, 16-wave version: wave owns 16 j-columns (c0 = wave*16), both
// 16-row batch tiles (m = 0,1). 20 MFMA/wave. MFMA accumulates in place on
// hst (C-in = h; bc rides in win[1]'s k=33 slot against the constant-1.0
// x column). One lgkm-only barrier; stores never drained in-loop.
#define CSTEP(HR, XR, HW, XW, T)                                              \
  {                                                                           \
    float xp0 = 0.f, xp1 = 0.f;                                               \
    const bool more = (T) + 1 < T_SEQ;                                        \
    if (more) {                                                               \
      const float* xt1 = xpf + (size_t)((T) + 1) * xstep;                     \
      xp0 = xt1[e0];                                                          \
      if (p1) xp1 = xt1[e1];                                                  \
    }                                                                         \
    const short* hb = lds + (HR);                                             \
    const short* xb = lds + (XR);                                             \
    _Pragma("unroll") for (int ks = 0; ks < 8; ++ks) {                        \
      const int k = ks * 32 + kq * 8;                                         \
      short8 a0 = *(const short8*)(hb + colA * H_STRIDE + k);                 \
      short8 a1 = *(const short8*)(hb + (16 + colA) * H_STRIDE + k);          \
      hst[0] = MFMA(a0, wf[ks], hst[0]);                                      \
      hst[1] = MFMA(a1, wf[ks], hst[1]);                                      \
    }                                                                         \
    _Pragma("unroll") for (int kb = 0; kb < 2; ++kb) {                        \
      const int k = kb * 32 + kq * 8;                                         \
      short8 a0 = *(const short8*)(xb + colA * X_STRIDE + k);                 \
      short8 a1 = *(const short8*)(xb + (16 + colA) * X_STRIDE + k);          \
      hst[0] = MFMA(a0, win[kb], hst[0]);                                     \
      hst[1] = MFMA(a1, win[kb], hst[1]);                                     \
    }                                                                         \
    _Pragma("unroll") for (int m = 0; m < 2; ++m)                             \
      _Pragma("unroll") for (int i = 0; i < 4; ++i) {                         \
        float hn = fmaxf(0.5f * hst[m][i], 0.0f);                             \
        hst[m][i] = hn;                                                       \
        outp[(m * 16 + i) * HID] = hn;                                        \
      }                                                                       \
    _Pragma("unroll") for (int m = 0; m < 2; ++m)                             \
      _Pragma("unroll") for (int i = 0; i < 4; ++i)                           \
        lds[(HW) + (m * 16 + kq * 4 + i) * H_STRIDE + c0 + colA] =            \
            f2bf(hst[m][i]);                                                  \
    if (more) {                                                               \
      lds[(XW) + r0 * X_STRIDE + c0x] = f2bf(xp0);                            \
      if (p1) lds[(XW) + r1 * X_STRIDE + c1x] = f2bf(xp1);                    \
    }                                                                         \
    __builtin_amdgcn_sched_barrier(0);                                        \
    asm volatile("s_waitcnt lgkmcnt(0)" ::: "memory");                        \
    __builtin_amdgcn_s_barrier();                                             \
    __builtin_amdgcn_sched_barrier(0);                                        \
    outp += outstep;                                                          \
  }

__global__ __launch_bounds__(NTH, 4)
void ctrnn_kernel(const float* __restrict__ x, const int* __restrict__ sub_id,
                  const float* __restrict__ gates, const float* __restrict__ W_in,
                  const float* __restrict__ b_in, const float* __restrict__ W_h,
                  const float* __restrict__ b_h, float* __restrict__ out)
{
  __shared__ short lds[LDS_SHORTS];
  const int tid  = threadIdx.x;
  const int lane = tid & 63;
  const int wave = tid >> 6;    // 0..15
  const int colA = lane & 15;   // A-row (batch) / C-col within tile
  const int kq   = lane >> 4;   // k-chunk / C-row group
  const int c0   = wave * 16;   // wave's hidden-j base (16 waves x 16 j)
  const int brow0 = blockIdx.x * BTILE;

  const int sid = sub_id[0];
  const float* grow = gates + sid * HID;

  // ---- zero all LDS; then x col 33 = 1.0 (bf16 0x3F80) in BOTH x buffers ----
  {
    int* ldsi = (int*)lds;
    for (int i = tid; i < LDS_SHORTS / 2; i += NTH) ldsi[i] = 0;
  }
  __syncthreads();
  if (tid < 2 * BTILE) {
    int b = tid >> 5, r = tid & 31;
    lds[(b ? X1 : X0) + r * X_STRIDE + 33] = (short)0x3F80;
  }

  // ---- t-invariant operands in registers (per wave: 16 out-cols) ----
  short8 wf[8];    // W_h' = diag(g)*W_h B-fragments (32 VGPRs)
  short8 win[2];   // W_in B-fragments; k=33 slot carries bc
  {
    const int col = c0 + colA;
    const float g = grow[col];
    #pragma unroll
    for (int ks = 0; ks < 8; ++ks) {
      const float* wp = W_h + col * HID + ks * 32 + kq * 8;
      float4v w0 = *(const float4v*)wp;
      float4v w1 = *(const float4v*)(wp + 4);
      short8 f;
      f[0] = f2bf(g * w0[0]); f[1] = f2bf(g * w0[1]);
      f[2] = f2bf(g * w0[2]); f[3] = f2bf(g * w0[3]);
      f[4] = f2bf(g * w1[0]); f[5] = f2bf(g * w1[1]);
      f[6] = f2bf(g * w1[2]); f[7] = f2bf(g * w1[3]);
      wf[ks] = f;
    }
    const float bcv = b_in[col] + g * b_h[col];
    #pragma unroll
    for (int kb = 0; kb < 2; ++kb) {
      short8 f;
      #pragma unroll
      for (int j = 0; j < 8; ++j) {
        const int kk = kb * 32 + kq * 8 + j;
        float v = (kk < INPUT) ? W_in[col * INPUT + kk]
                               : (kk == INPUT ? bcv : 0.0f);
        f[j] = f2bf(v);
      }
      win[kb] = f;
    }
  }

  __syncthreads();   // zero + col-33 writes complete before x0 staging

  // ---- stage x_0 into buffer 0 ----
  {
    const float* xt = x + (size_t)brow0 * INPUT;
    for (int e = tid; e < BTILE * INPUT; e += NTH) {
      int r = e / INPUT, c = e - r * INPUT;
      lds[X0 + r * X_STRIDE + c] = f2bf(xt[e]);
    }
  }

  // x-prefetch invariants (1056 elems over 1024 threads, 2 rounds)
  const int e0 = tid, e1 = tid + NTH;
  const int r0 = e0 / INPUT, c0x = e0 - r0 * INPUT;
  const int r1 = e1 / INPUT, c1x = e1 - r1 * INPUT;
  const bool p1 = (e1 < BTILE * INPUT);

  // persistent f32 h at MFMA C-layout: hst[m][i] =
  //   h[b = brow0 + m*16 + kq*4 + i][j = c0 + colA]; MFMA accumulates on it
  float4v hst[2];
  #pragma unroll
  for (int m = 0; m < 2; ++m)
    #pragma unroll
    for (int i = 0; i < 4; ++i) hst[m][i] = 0.0f;

  float* outp = out + (size_t)(brow0 + kq * 4) * HID + c0 + colA;
  const int outstep = BATCH * HID;
  const float* xpf = x + (size_t)brow0 * INPUT;
  const int xstep = BATCH * INPUT;

  __syncthreads();   // x0 staged; h0 zeroed

  #pragma unroll 1
  for (int t2 = 0; t2 < T_SEQ / 2; ++t2) {
    CSTEP(H0, X0, H1, X1, 2 * t2);       // even: read buf0, write buf1
    CSTEP(H1, X1, H0, X0, 2 * t2 + 1);   // odd:  read buf1, write buf0
  }

  // h_last = h after step T-1 (in registers)
  {
    float* hp = out + (size_t)T_SEQ * BATCH * HID +
                (size_t)(brow0 + kq * 4) * HID + c0 + colA;
    #pragma unroll
    for (int m = 0; m < 2; ++m)
      #pragma unroll
      for (int i = 0; i < 4; ++i)
        hp[(m * 16 + i) * HID] = hst[m][i];
  }
}

extern "C" void kernel_launch(void* const* d_in, const int* in_sizes, int n_in,
                              void* d_out, int out_size, void* d_ws, size_t ws_size,
                              hipStream_t stream) {
  const float* x    = (const float*)d_in[0];
  const int*   sid  = (const int*)  d_in[1];
  const float* gts  = (const float*)d_in[2];
  const float* W_in = (const float*)d_in[3];
  const float* b_in = (const float*)d_in[4];
  const float* W_h  = (const float*)d_in[5];
  const float* b_h  = (const float*)d_in[6];
  float* out = (float*)d_out;

  ctrnn_kernel<<<BATCH / BTILE, NTH, 0, stream>>>(x, sid, gts, W_in, b_in, W_h, b_h, out);
}